// Round 5
// baseline (426.309 us; speedup 1.0000x reference)
//
#include <hip/hip_runtime.h>

// LSTM: B=2048, T=512, I=1, H=64, L=2, O=1. fp32 in/out.
// Round 17: role-split waves + fused-denominator gates.
//   r14/r15/r16 all show MfmaUtil+VALUBusy ~= 98%: pipes serialized because
//   every wave's VALU is RAW-dependent on its own same-step MFMAs and all
//   waves are symmetric. Fix = heterogeneous waves (r12 was the only
//   geometry with sum>100%):
//     1024 thr / 16 waves. Waves 0-7: L1 role (2 tiles, 6 MFMA, 1 packed
//     gate pass). Waves 8-15: L2 role, skewed one step (12 MFMA, 1 pass).
//     Per SIMD: 2 L1 + 2 L2 waves -> L1 gate-VALU runs under L2 matrix
//     time. s_setprio(1) on L1 waves (producer chain) per T5.
//   VALU cut: fused-denominator gates, 10 -> 7 trans ops per gate4:
//     c' = [c*A*B + (B-2)*F] / (A*B*F),  A=1+e^-i, B=1+e^2g, F=1+e^-f
//     h  = (C-2) / ((1+e^-o)*C),         C=1+e^2c'
//   (one rcp per group; fminf guard on the c-exp arg kills the inf*0 case).
// Unchanged: i8 16x16x64 limb scheme (W=(hi*256+lo)/260096, h/32512, lo
// offset-binary, corr folded into acc-init), sigma byte-permute stores,
// dpp_ror8 tile-pair packing (all-lanes-active call sites).

#define TT 512
#define HH 64
#define BT 8

typedef __attribute__((ext_vector_type(4))) int i32x4;

#define MFMAI8 __builtin_amdgcn_mfma_i32_16x16x64_i8

#define WSCALE 260096.0f   /* 32512 / 0.125 */
#define HSCALE 32512.0f    /* |h| <= 1      */
#define LOG2E  1.44269504f
constexpr float C_SIG = (float)(256.0 / (260096.0 * 32512.0) * 1.4426950408889634);
constexpr float C_TGH = (float)(2.0 * 256.0 / (260096.0 * 32512.0) * 1.4426950408889634);

__device__ __forceinline__ float exp2_hw(float x) {
    float r; asm("v_exp_f32 %0, %1" : "=v"(r) : "v"(x)); return r;
}
__device__ __forceinline__ float exp2n_hw(float x) {
    float r; asm("v_exp_f32 %0, -%1" : "=v"(r) : "v"(x)); return r;
}
// Fused-denominator LSTM gates. Inputs pre-scaled: p0,p1,p3 by log2e,
// p2 by 2*log2e. c in real units. 5 exp + 2 rcp (was 5+5).
__device__ __forceinline__ float gate4f(float p0, float p1, float p2, float p3, float& c) {
    float ia = exp2n_hw(p0);            // e^{-i}
    float fb = exp2n_hw(p1);            // e^{-f}
    float gb = exp2_hw(p2);             // e^{2g}
    float ob = exp2n_hw(p3);            // e^{-o}
    float A = 1.f + ia, B = 1.f + gb, F = 1.f + fb;
    float t1  = A * B;
    float den = t1 * F;
    float num = fmaf(c, t1, (B - 2.f) * F);
    c = num * __builtin_amdgcn_rcpf(den);
    float e2 = exp2_hw(fminf(c * (2.f * LOG2E), 126.f));   // guard inf*0
    float C  = 1.f + e2;
    float r2 = __builtin_amdgcn_rcpf((1.f + ob) * C);
    return (C - 2.f) * r2;
}
// lane i <- lane (i^8) within each row of 16 (row_ror:8, HW-verified r6).
// All 64 lanes active at every call site (enclosing branches wave-uniform).
__device__ __forceinline__ int dpp_ror8_i(int v) {
    return __builtin_amdgcn_update_dpp(v, v, 0x128, 0xF, 0xF, true);
}
// 16 fp32 weights of one row-quarter -> i8 hi/lo limb frags, sigma-permuted:
// byte b of reg r holds W[base + 4*b + r].
__device__ __forceinline__ void cvtW16(const float* __restrict__ p, i32x4& hi, i32x4& lo) {
    #pragma unroll
    for (int r = 0; r < 4; ++r) {
        int hw = 0, lw = 0;
        #pragma unroll
        for (int b = 0; b < 4; ++b) {
            int wq = (int)rintf(p[4 * b + r] * WSCALE);   // |wq| <= 32512
            int h8 = (wq + 128) >> 8;                     // [-127,127]
            int l8 = wq - (h8 << 8);                      // [-128,127]
            hw |= (h8 & 0xFF) << (8 * b);
            lw |= (l8 & 0xFF) << (8 * b);
        }
        hi[r] = hw; lo[r] = lw;
    }
}

__global__ __launch_bounds__(1024) void lstm_mfma(
    const float* __restrict__ x,
    const float* __restrict__ Wih0, const float* __restrict__ Whh0,
    const float* __restrict__ bih0, const float* __restrict__ bhh0,
    const float* __restrict__ Wih1, const float* __restrict__ Whh1,
    const float* __restrict__ bih1, const float* __restrict__ bhh1,
    const float* __restrict__ fcW, const float* __restrict__ fcb,
    float* __restrict__ out)
{
    __shared__ float xs[BT][TT + 1];                        // 16.4 KB
    // h limbs in i8 B-layout: [layer][buf][limb][row][byte];
    // byte jj of row holds unit u = (row>>4)*16 + sigma(jj). Lo-plane is
    // offset-binary (hq^0x80); encoded zero = 0x80. Junk rows keep init.
    __shared__ __align__(16) signed char aH[2][2][2][64][16];  // 8 KB
    __shared__ float hF[BT][HH + 1];
    __shared__ float fcw_s[HH];

    const int t    = threadIdx.x;     // 0..1023
    const int lane = t & 63;
    const int w    = t >> 6;          // wave 0..15
    const bool isL1 = (w < 8);
    const int wv   = w & 7;           // group-local wave: tiles 2wv, 2wv+1
    const int b0   = blockIdx.x * BT;
    const int m    = lane & 15;
    const int q    = lane >> 4;
    const int ts   = m >> 3;          // tile-select within the pair
    const int bpk  = m & 7;           // this lane's batch
    const int j    = 8 * wv + 4 * ts + q;   // this lane's hidden unit

    // ---- stage x; init limb planes (hi=0, lo=0x80 = encoded zero) ----
    for (int i = t; i < BT * TT; i += 1024)
        xs[i >> 9][i & (TT - 1)] = x[(size_t)(b0 + (i >> 9)) * TT + (i & (TT - 1))];
    {
        int* z = (int*)aH;
        for (int i = t; i < 2048; i += 1024)
            z[i] = ((i >> 8) & 1) ? 0x80808080 : 0;   // 256 ints per limb plane
    }
    if (t < HH) fcw_s[t] = fcW[t];

    // ---- persistent A-frag weights (i8 limbs), role-dependent ----
    // A-row m in tile ti -> gate-row rho = (m&3)*64 + 4*ti + (m>>2)
    // L1 waves: slot0 = Whh0.  L2 waves: slot0 = Wih1, slot1 = Whh1.
    i32x4 Wh[2][2], Wl[2][2];   // [tile][slot]
    i32x4 corr[2];
    {
        i32x4 ones; ones[0] = 0x01010101; ones[1] = 0x01010101;
        ones[2] = 0x01010101; ones[3] = 0x01010101;
        i32x4 zz = {0, 0, 0, 0};
        #pragma unroll
        for (int i = 0; i < 2; ++i) {
            const int rho = (m & 3) * 64 + 4 * (2 * wv + i) + (m >> 2);
            if (isL1) {
                cvtW16(Whh0 + rho * HH + q * 16, Wh[i][0], Wl[i][0]);
                i32x4 S = MFMAI8(Wh[i][0], ones, zz, 0, 0, 0);
                #pragma unroll
                for (int r = 0; r < 4; ++r) corr[i][r] = S[r] << 7;
            } else {
                cvtW16(Wih1 + rho * HH + q * 16, Wh[i][0], Wl[i][0]);
                cvtW16(Whh1 + rho * HH + q * 16, Wh[i][1], Wl[i][1]);
                i32x4 S = MFMAI8(Wh[i][1], ones, MFMAI8(Wh[i][0], ones, zz, 0, 0, 0), 0, 0, 0);
                #pragma unroll
                for (int r = 0; r < 4; ++r) corr[i][r] = S[r] << 7;
            }
        }
    }

    // ---- per-lane combine constants (pre-scaled into exp2 domain) ----
    float wxb[4], bia[4];
    #pragma unroll
    for (int g = 0; g < 4; ++g) {
        const int r = g * 64 + j;
        const float sc = (g == 2) ? 2.f * LOG2E : LOG2E;
        if (isL1) { wxb[g] = Wih0[r] * sc; bia[g] = (bih0[r] + bhh0[r]) * sc; }
        else      { wxb[g] = 0.f;          bia[g] = (bih1[r] + bhh1[r]) * sc; }
    }
    // scatter target: row wl, byte wb = sigma(j&15)
    const int wl = ((j >> 4) << 4) + bpk;
    const int wb = ((j & 3) << 2) | ((j >> 2) & 3);
    float c = 0.f;

    if (isL1) __builtin_amdgcn_s_setprio(1);   // favor the producer chain (T5)

    __syncthreads();

    // ---- peeled k=0: L1 computes h1(0); L2 idles (enc-zero init is exact) --
    if (isL1) {
        i32x4 bh1 = *(const i32x4*)&aH[0][0][0][lane][0];
        i32x4 bl1 = *(const i32x4*)&aH[0][0][1][lane][0];
        i32x4 z4 = {0, 0, 0, 0};
        i32x4 HHa[2], MDa[2];
        #pragma unroll
        for (int i = 0; i < 2; ++i) {
            HHa[i] = MFMAI8(Wh[i][0], bh1, z4, 0, 0, 0);
            MDa[i] = MFMAI8(Wl[i][0], bh1, MFMAI8(Wh[i][0], bl1, corr[i], 0, 0, 0), 0, 0, 0);
        }
        float xb = xs[bpk][0];
        float pre[4];
        #pragma unroll
        for (int r = 0; r < 4; ++r) {
            int Pa = (HHa[0][r] << 8) + MDa[0][r];
            int Pb = (HHa[1][r] << 8) + MDa[1][r];
            int P  = Pa + dpp_ror8_i(Pb);
            const float Cr = (r == 2) ? C_TGH : C_SIG;
            pre[r] = fmaf((float)P, Cr, fmaf(wxb[r], xb, bia[r]));
        }
        float hv = gate4f(pre[0], pre[1], pre[2], pre[3], c);
        int hq = __float_as_int(fmaf(hv, HSCALE, 12582912.f)) - 0x4B400000;
        aH[0][1][0][wl][wb] = (signed char)(hq >> 8);
        aH[0][1][1][wl][wb] = (signed char)(hq ^ 0x80);
    }
    __syncthreads();

    // ---- main loop k=1..511: L1 waves -> h1(k); L2 waves -> h2(k-1) ----
    #pragma unroll 2
    for (int k = 1; k < TT; ++k) {
        const int p = k & 1, pn = p ^ 1;
        if (isL1) {
            i32x4 bh1 = *(const i32x4*)&aH[0][p][0][lane][0];
            i32x4 bl1 = *(const i32x4*)&aH[0][p][1][lane][0];
            i32x4 z4 = {0, 0, 0, 0};
            i32x4 HHa[2], MDa[2];
            #pragma unroll
            for (int i = 0; i < 2; ++i) {
                HHa[i] = MFMAI8(Wh[i][0], bh1, z4, 0, 0, 0);
                MDa[i] = MFMAI8(Wl[i][0], bh1, MFMAI8(Wh[i][0], bl1, corr[i], 0, 0, 0), 0, 0, 0);
            }
            float xb = xs[bpk][k];
            float pre[4];
            #pragma unroll
            for (int r = 0; r < 4; ++r) {
                int Pa = (HHa[0][r] << 8) + MDa[0][r];
                int Pb = (HHa[1][r] << 8) + MDa[1][r];
                int P  = Pa + dpp_ror8_i(Pb);
                const float Cr = (r == 2) ? C_TGH : C_SIG;
                pre[r] = fmaf((float)P, Cr, fmaf(wxb[r], xb, bia[r]));
            }
            float hv = gate4f(pre[0], pre[1], pre[2], pre[3], c);
            int hq = __float_as_int(fmaf(hv, HSCALE, 12582912.f)) - 0x4B400000;
            aH[0][pn][0][wl][wb] = (signed char)(hq >> 8);
            aH[0][pn][1][wl][wb] = (signed char)(hq ^ 0x80);
        } else {
            i32x4 bh1 = *(const i32x4*)&aH[0][p][0][lane][0];
            i32x4 bl1 = *(const i32x4*)&aH[0][p][1][lane][0];
            i32x4 bh2 = *(const i32x4*)&aH[1][p][0][lane][0];
            i32x4 bl2 = *(const i32x4*)&aH[1][p][1][lane][0];
            i32x4 z4 = {0, 0, 0, 0};
            i32x4 HHb[2], MDb[2];
            #pragma unroll
            for (int i = 0; i < 2; ++i) {
                HHb[i] = MFMAI8(Wh[i][1], bh2, MFMAI8(Wh[i][0], bh1, z4, 0, 0, 0), 0, 0, 0);
                MDb[i] = MFMAI8(Wl[i][1], bh2,
                         MFMAI8(Wh[i][1], bl2,
                         MFMAI8(Wl[i][0], bh1,
                         MFMAI8(Wh[i][0], bl1, corr[i], 0, 0, 0), 0, 0, 0), 0, 0, 0), 0, 0, 0);
            }
            float pre[4];
            #pragma unroll
            for (int r = 0; r < 4; ++r) {
                int Pa = (HHb[0][r] << 8) + MDb[0][r];
                int Pb = (HHb[1][r] << 8) + MDb[1][r];
                int P  = Pa + dpp_ror8_i(Pb);
                const float Cr = (r == 2) ? C_TGH : C_SIG;
                pre[r] = fmaf((float)P, Cr, bia[r]);
            }
            float hv = gate4f(pre[0], pre[1], pre[2], pre[3], c);
            int hq = __float_as_int(fmaf(hv, HSCALE, 12582912.f)) - 0x4B400000;
            aH[1][pn][0][wl][wb] = (signed char)(hq >> 8);
            aH[1][pn][1][wl][wb] = (signed char)(hq ^ 0x80);
        }
        __syncthreads();
    }

    // ---- epilogue: h2(TT-1) from h1(TT-1) and h2(TT-2) (both in buf 0) ----
    if (!isL1) {
        i32x4 bh1 = *(const i32x4*)&aH[0][0][0][lane][0];
        i32x4 bl1 = *(const i32x4*)&aH[0][0][1][lane][0];
        i32x4 bh2 = *(const i32x4*)&aH[1][0][0][lane][0];
        i32x4 bl2 = *(const i32x4*)&aH[1][0][1][lane][0];
        i32x4 z4 = {0, 0, 0, 0};
        i32x4 HHb[2], MDb[2];
        #pragma unroll
        for (int i = 0; i < 2; ++i) {
            HHb[i] = MFMAI8(Wh[i][1], bh2, MFMAI8(Wh[i][0], bh1, z4, 0, 0, 0), 0, 0, 0);
            MDb[i] = MFMAI8(Wl[i][1], bh2,
                     MFMAI8(Wh[i][1], bl2,
                     MFMAI8(Wl[i][0], bh1,
                     MFMAI8(Wh[i][0], bl1, corr[i], 0, 0, 0), 0, 0, 0), 0, 0, 0), 0, 0, 0);
        }
        float pre[4];
        #pragma unroll
        for (int r = 0; r < 4; ++r) {
            int Pa = (HHb[0][r] << 8) + MDb[0][r];
            int Pb = (HHb[1][r] << 8) + MDb[1][r];
            int P  = Pa + dpp_ror8_i(Pb);
            const float Cr = (r == 2) ? C_TGH : C_SIG;
            pre[r] = fmaf((float)P, Cr, bia[r]);
        }
        float hv = gate4f(pre[0], pre[1], pre[2], pre[3], c);
        hF[bpk][j] = hv;
    }
    __syncthreads();

    // ---- final FC: out[b] = fcW . h2(TT-1)[b] + fcb ----
    if (t < BT) {
        float s = fcb[0];
        #pragma unroll 8
        for (int jj = 0; jj < HH; ++jj)
            s = fmaf(hF[t][jj], fcw_s[jj], s);
        out[b0 + t] = s;
    }
}

extern "C" void kernel_launch(void* const* d_in, const int* in_sizes, int n_in,
                              void* d_out, int out_size, void* d_ws, size_t ws_size,
                              hipStream_t stream) {
    const float* x    = (const float*)d_in[0];
    const float* Wih0 = (const float*)d_in[1];
    const float* Whh0 = (const float*)d_in[2];
    const float* bih0 = (const float*)d_in[3];
    const float* bhh0 = (const float*)d_in[4];
    const float* Wih1 = (const float*)d_in[5];
    const float* Whh1 = (const float*)d_in[6];
    const float* bih1 = (const float*)d_in[7];
    const float* bhh1 = (const float*)d_in[8];
    const float* fcW  = (const float*)d_in[9];
    const float* fcb  = (const float*)d_in[10];
    float* out = (float*)d_out;

    lstm_mfma<<<dim3(2048 / BT), dim3(1024), 0, stream>>>(
        x, Wih0, Whh0, bih0, bhh0, Wih1, Whh1, bih1, bhh1, fcW, fcb, out);
}